// Round 1
// baseline (250.082 us; speedup 1.0000x reference)
//
#include <hip/hip_runtime.h>
#include <stdint.h>

#define N_NODES 100000
#define N_EDGES 3200000
#define N_ELEMS 10
#define N_PAIRS (N_ELEMS * N_ELEMS)

// ---------------------------------------------------------------------------
// Kernel 1: per-node element index = argmax over the 10-wide node_attrs row.
// Rows are 40 B apart -> 8 B aligned, so five float2 loads per row.
// First-max-wins (strict >) matches jnp.argmax tie semantics.
// ---------------------------------------------------------------------------
__global__ __launch_bounds__(256) void node_elem_kernel(
    const float* __restrict__ node_attrs,
    uint8_t* __restrict__ node_elem, int n) {
  int i = blockIdx.x * blockDim.x + threadIdx.x;
  if (i >= n) return;
  const float2* row = (const float2*)(node_attrs + (size_t)i * N_ELEMS);
  float best = -INFINITY;
  int bj = 0;
#pragma unroll
  for (int k = 0; k < 5; ++k) {
    float2 v = row[k];
    if (v.x > best) { best = v.x; bj = 2 * k; }
    if (v.y > best) { best = v.y; bj = 2 * k + 1; }
  }
  node_elem[i] = (uint8_t)bj;
}

// ---------------------------------------------------------------------------
// Kernel 2: 100-entry pair table. Only 10 distinct atomic numbers exist, so
// all powf/radii work collapses here (one tiny 1-block kernel).
// tab[pi] = { 1/a, 0.5*14.3996*Zu*Zv, r_max, 1/r_max }
// ---------------------------------------------------------------------------
__global__ void pair_table_kernel(const int* __restrict__ atomic_numbers,
                                  const float* __restrict__ covalent_radii,
                                  float4* __restrict__ pair_tab) {
  int t = threadIdx.x;
  if (t >= N_PAIRS) return;
  int eu = t / N_ELEMS, ev = t % N_ELEMS;
  int Zu = atomic_numbers[eu];
  int Zv = atomic_numbers[ev];
  float Zuf = (float)Zu, Zvf = (float)Zv;
  float a = 0.4543f * 0.529f / (powf(Zuf, 0.3f) + powf(Zvf, 0.3f));
  float ainv = 1.0f / a;
  float pref = 0.5f * 14.3996f * Zuf * Zvf;
  float rmax = covalent_radii[Zu] + covalent_radii[Zv];
  pair_tab[t] = make_float4(ainv, pref, rmax, 1.0f / rmax);
}

// ---------------------------------------------------------------------------
// Kernel 3: per-edge energy + scatter-add into receiver nodes.
// envelope(p=6): 1 - 28 r^6 + 48 r^7 - 21 r^8, masked by (x < r_max).
// ---------------------------------------------------------------------------
__global__ __launch_bounds__(256) void edge_kernel(
    const float* __restrict__ x,
    const int* __restrict__ edge_index,   // [2, E]: senders then receivers
    const uint8_t* __restrict__ node_elem,
    const float4* __restrict__ pair_tab,
    float* __restrict__ out, int n_edges) {
  __shared__ float4 s_tab[N_PAIRS];
  for (int t = threadIdx.x; t < N_PAIRS; t += blockDim.x) s_tab[t] = pair_tab[t];
  __syncthreads();

  int i = blockIdx.x * blockDim.x + threadIdx.x;
  if (i >= n_edges) return;

  float xi = x[i];
  int u = edge_index[i];
  int v = edge_index[n_edges + i];
  int eu = node_elem[u];
  int ev = node_elem[v];
  float4 tb = s_tab[eu * N_ELEMS + ev];

  float roa = xi * tb.x;
  float phi = 0.1818f  * __expf(-3.2f    * roa)
            + 0.5099f  * __expf(-0.9423f * roa)
            + 0.2802f  * __expf(-0.4028f * roa)
            + 0.02817f * __expf(-0.2016f * roa);
  float val = tb.y * phi / xi;

  float r  = xi * tb.w;          // x / r_max
  float r2 = r * r;
  float r3 = r2 * r;
  float r6 = r3 * r3;
  float env = 1.0f - 28.0f * r6 + 48.0f * r6 * r - 21.0f * r6 * r2;

  val = (xi < tb.z) ? val * env : 0.0f;
  atomicAdd(&out[v], val);
}

// ---------------------------------------------------------------------------
extern "C" void kernel_launch(void* const* d_in, const int* in_sizes, int n_in,
                              void* d_out, int out_size, void* d_ws, size_t ws_size,
                              hipStream_t stream) {
  const float* x              = (const float*)d_in[0];
  const float* node_attrs     = (const float*)d_in[1];
  const int*   edge_index     = (const int*)d_in[2];
  const int*   atomic_numbers = (const int*)d_in[3];
  const float* covalent_radii = (const float*)d_in[4];
  float* out = (float*)d_out;

  // workspace layout: [0, 100000) uint8 node_elem; [100000, +1600) float4 pair table
  uint8_t* node_elem = (uint8_t*)d_ws;
  float4*  pair_tab  = (float4*)((char*)d_ws + N_NODES);  // 100000 is 16B-aligned

  // d_out is poisoned 0xAA before every timed call -> zero it (capturable).
  hipMemsetAsync(d_out, 0, (size_t)out_size * sizeof(float), stream);

  node_elem_kernel<<<(N_NODES + 255) / 256, 256, 0, stream>>>(
      node_attrs, node_elem, N_NODES);
  pair_table_kernel<<<1, 128, 0, stream>>>(atomic_numbers, covalent_radii, pair_tab);
  edge_kernel<<<(N_EDGES + 255) / 256, 256, 0, stream>>>(
      x, edge_index, node_elem, pair_tab, out, N_EDGES);
}